// Round 8
// baseline (44.058 us; speedup 1.0000x reference)
//
#include <hip/hip_runtime.h>

#define TPB 256
#define PER_THREAD 32
#define CHUNK (TPB * PER_THREAD)     // 8192 elements per block
#define WCHUNK (64 * PER_THREAD)     // 2048 elements per wave
#define NQ 8                         // float4 loads per lane per wave

// ---------------------------------------------------------------------------
// Exclusive block-wide scan of one unsigned per thread (tid order).
// ---------------------------------------------------------------------------
__device__ __forceinline__ unsigned block_excl_scan(unsigned tsum, unsigned* wtot) {
    const int lane = threadIdx.x & 63;
    const int wid  = threadIdx.x >> 6;
    unsigned v = tsum;
#pragma unroll
    for (int off = 1; off < 64; off <<= 1) {
        unsigned u = __shfl_up(v, off, 64);
        if (lane >= off) v += u;
    }
    if (lane == 63) wtot[wid] = v;
    __syncthreads();
    unsigned woff = 0;
    for (int w = 0; w < wid; ++w) woff += wtot[w];
    return woff + v - tsum;   // exclusive prefix for this thread
}

// ---------------------------------------------------------------------------
// Pass 1: wave-coalesced score read with EXPLICIT 8-deep load batching
// (defeats the compiler's load-sinking; 8 outstanding loads per wave).
// Mask word g covers elements [32g, 32g+32) in global element order.
// ---------------------------------------------------------------------------
__global__ void k_count(const float* __restrict__ score,
                        unsigned* __restrict__ blockCount,
                        unsigned* __restrict__ mask, long n) {
    const int  tid  = threadIdx.x;
    const int  lane = tid & 63, w = tid >> 6;
    const long base  = (long)blockIdx.x * CHUNK;
    const long wbase = base + (long)w * WCHUNK;
    unsigned cnt = 0;

    if (base + CHUNK <= n) {
        const float4* s4 = reinterpret_cast<const float4*>(score);
        float4 buf[NQ];
#pragma unroll
        for (int q = 0; q < NQ; ++q)          // batch ALL loads first (MLP=8)
            buf[q] = s4[wbase / 4 + 64 * q + lane];
#pragma unroll
        for (int q = 0; q < NQ; ++q) {
            float4 v = buf[q];
            unsigned nib = (unsigned)(v.x > 0.f)        | ((unsigned)(v.y > 0.f) << 1)
                         | ((unsigned)(v.z > 0.f) << 2) | ((unsigned)(v.w > 0.f) << 3);
            cnt += __popc(nib);
            unsigned part = nib << ((lane & 7) * 4);
            part |= __shfl_xor(part, 1);
            part |= __shfl_xor(part, 2);
            part |= __shfl_xor(part, 4);
            if ((lane & 7) == 0 && mask)
                mask[(wbase >> 5) + 8 * q + (lane >> 3)] = part;
        }
    } else {
        for (int q = 0; q < NQ; ++q) {
            unsigned nib = 0;
#pragma unroll
            for (int j = 0; j < 4; ++j) {
                long gi = wbase + 256 * q + 4 * lane + j;
                if (gi < n && score[gi] > 0.f) nib |= (1u << j);
            }
            cnt += __popc(nib);
            unsigned part = nib << ((lane & 7) * 4);
            part |= __shfl_xor(part, 1);
            part |= __shfl_xor(part, 2);
            part |= __shfl_xor(part, 4);
            if ((lane & 7) == 0 && mask)
                mask[(wbase >> 5) + 8 * q + (lane >> 3)] = part;
        }
    }

#pragma unroll
    for (int off = 32; off > 0; off >>= 1) cnt += __shfl_down(cnt, off, 64);
    __shared__ unsigned wsum[TPB / 64];
    if (lane == 0) wsum[w] = cnt;
    __syncthreads();
    if (tid == 0) {
        unsigned tot = 0;
        for (int i = 0; i < TPB / 64; ++i) tot += wsum[i];
        blockCount[blockIdx.x] = tot;
    }
}

// ---------------------------------------------------------------------------
// Pass 2: predict loads issued at the TOP (issue-early; HBM latency hides
// under the mask load + block scan + offset phase). Proven rank/math path.
// No fences, no atomics (rounds 3/5/6 lessons).
// ---------------------------------------------------------------------------
template <bool USE_MASK>
__global__ void k_main(const float* __restrict__ predict,
                       const float* __restrict__ score,
                       const unsigned* __restrict__ mask,
                       const unsigned* __restrict__ blockCount,
                       double* __restrict__ blockSum, long n, int B) {
    const int  tid  = threadIdx.x;
    const int  bid  = blockIdx.x;
    const int  lane = tid & 63, w = tid >> 6;
    const long base  = (long)bid * CHUNK;
    const long wbase = base + (long)w * WCHUNK;
    const bool full  = (base + CHUNK <= n);

    __shared__ unsigned wtot[TPB / 64];
    __shared__ unsigned wpart[2 * (TPB / 64)];
    __shared__ unsigned s_off, s_P;
    __shared__ double   dsum[TPB / 64];

    // --- issue predict loads FIRST (overlap with everything below) ---
    float4 pbuf[NQ];
    if (full) {
        const float4* p4 = reinterpret_cast<const float4*>(predict);
#pragma unroll
        for (int q = 0; q < NQ; ++q)
            pbuf[q] = p4[wbase / 4 + 64 * q + lane];
    }

    // --- this thread's mask word (its 32 contiguous elements) ---
    unsigned wd = 0;
    if (USE_MASK) {
        wd = mask[(size_t)bid * TPB + tid];
    } else {
        const long tb = base + (long)tid * PER_THREAD;
        if (tb + PER_THREAD <= n) {
            const float4* s4 = reinterpret_cast<const float4*>(score + tb);
#pragma unroll
            for (int q = 0; q < PER_THREAD / 4; ++q) {
                float4 v = s4[q];
                wd |= ((unsigned)(v.x > 0.f)) << (4 * q + 0);
                wd |= ((unsigned)(v.y > 0.f)) << (4 * q + 1);
                wd |= ((unsigned)(v.z > 0.f)) << (4 * q + 2);
                wd |= ((unsigned)(v.w > 0.f)) << (4 * q + 3);
            }
        } else {
            for (int e = 0; e < PER_THREAD; ++e) {
                long gi = tb + e;
                if (gi < n && score[gi] > 0.f) wd |= (1u << e);
            }
        }
    }

    unsigned cnt  = __popc(wd);
    unsigned excl = block_excl_scan(cnt, wtot);

    // --- per-block exclusive offset + global total P from blockCount ---
    unsigned offp = 0, tot = 0;
    for (int j = tid; j < B; j += TPB) {
        unsigned c = blockCount[j];
        tot  += c;
        offp += (j < bid) ? c : 0u;
    }
#pragma unroll
    for (int off = 32; off > 0; off >>= 1) {
        offp += __shfl_down(offp, off, 64);
        tot  += __shfl_down(tot,  off, 64);
    }
    if (lane == 0) { wpart[2 * w] = offp; wpart[2 * w + 1] = tot; }
    __syncthreads();
    if (tid == 0) {
        unsigned o = 0, t = 0;
        for (int i = 0; i < TPB / 64; ++i) { o += wpart[2 * i]; t += wpart[2 * i + 1]; }
        s_off = o; s_P = t;
    }
    __syncthreads();

    const unsigned P = s_P;
    const float invS = 1.0f / (float)P;                 // s value at positives
    const float sumS = (float)((double)invS * (double)P);
    const float rcpSumS = 1.0f / sumS;
    const float Pf = (float)P;

    const unsigned pre = s_off + excl;   // positives before this thread's word

    double acc = 0.0;
    if (full) {
#pragma unroll
        for (int q = 0; q < NQ; ++q) {
            const int t = 8 * q + (lane >> 3);
            const unsigned wq  = __shfl(wd,  t, 64);
            const unsigned prq = __shfl(pre, t, 64);
            const int nibStart = (lane & 7) * 4;
            unsigned run = prq + __popc(wq & ((1u << nibStart) - 1u));
            const unsigned nib = (wq >> nibStart) & 0xFu;
            float pv[4] = {pbuf[q].x, pbuf[q].y, pbuf[q].z, pbuf[q].w};
#pragma unroll
            for (int j = 0; j < 4; ++j) {
                const bool ispos = (nib >> j) & 1u;
                const unsigned newrun = run + (ispos ? 1u : 0u);
                const long gi = wbase + 256 * q + 4 * lane + j;
                const float p = pv[j] * rcpSumS;
                const float kp1  = (float)(newrun + 1u);
                const float posv = p * __builtin_amdgcn_rcpf(kp1)
                                 - invS * __builtin_amdgcn_rcpf(__log2f(kp1));
                const unsigned mr = (unsigned)(gi + 1) - newrun;
                const float negv  = p * __builtin_amdgcn_rcpf(Pf + (float)mr + 1.0f);
                const float tt = ispos ? posv : negv;
                acc += (double)(tt * tt);
                run = newrun;
            }
        }
    } else {
        for (int q = 0; q < NQ; ++q) {
            const int t = 8 * q + (lane >> 3);
            const unsigned wq  = __shfl(wd,  t, 64);
            const unsigned prq = __shfl(pre, t, 64);
            const int nibStart = (lane & 7) * 4;
            unsigned run = prq + __popc(wq & ((1u << nibStart) - 1u));
            const unsigned nib = (wq >> nibStart) & 0xFu;
            for (int j = 0; j < 4; ++j) {
                const long gi = wbase + 256 * q + 4 * lane + j;
                if (gi >= n) continue;
                const bool ispos = (nib >> j) & 1u;
                const unsigned newrun = run + (ispos ? 1u : 0u);
                const float p = predict[gi] * rcpSumS;
                const float kp1  = (float)(newrun + 1u);
                const float posv = p * __builtin_amdgcn_rcpf(kp1)
                                 - invS * __builtin_amdgcn_rcpf(__log2f(kp1));
                const unsigned mr = (unsigned)(gi + 1) - newrun;
                const float negv  = p * __builtin_amdgcn_rcpf(Pf + (float)mr + 1.0f);
                const float tt = ispos ? posv : negv;
                acc += (double)(tt * tt);
                run = newrun;
            }
        }
    }

    // --- deterministic block reduce ---
#pragma unroll
    for (int off = 32; off > 0; off >>= 1) acc += __shfl_down(acc, off, 64);
    if (lane == 0) dsum[w] = acc;
    __syncthreads();
    if (tid == 0) {
        double t = 0.0;
        for (int i = 0; i < TPB / 64; ++i) t += dsum[i];
        blockSum[bid] = t;
    }
}

// ---------------------------------------------------------------------------
// Pass 3: deterministic reduce of per-block doubles -> float scalar.
// ---------------------------------------------------------------------------
__global__ void k_final(const double* __restrict__ blockSum,
                        float* __restrict__ out, int B) {
    const int tid = threadIdx.x;
    double acc = 0.0;
    for (int j = tid; j < B; j += TPB) acc += blockSum[j];
#pragma unroll
    for (int off = 32; off > 0; off >>= 1) acc += __shfl_down(acc, off, 64);
    __shared__ double dsum[TPB / 64];
    const int lane = tid & 63, wid = tid >> 6;
    if (lane == 0) dsum[wid] = acc;
    __syncthreads();
    if (tid == 0) {
        double tot = 0.0;
        for (int w = 0; w < TPB / 64; ++w) tot += dsum[w];
        out[0] = (float)tot;
    }
}

extern "C" void kernel_launch(void* const* d_in, const int* in_sizes, int n_in,
                              void* d_out, int out_size, void* d_ws, size_t ws_size,
                              hipStream_t stream) {
    const float* predict = (const float*)d_in[0];
    const float* score   = (const float*)d_in[1];
    const long n = (long)in_sizes[0];
    const int B = (int)((n + CHUNK - 1) / CHUNK);   // 2048 for N=2^24

    unsigned char* ws = (unsigned char*)d_ws;
    size_t off = 0;
    unsigned* blockCount = (unsigned*)(ws + off); off += (size_t)B * sizeof(unsigned);
    off = (off + 255) & ~(size_t)255;
    double*   blockSum   = (double*)(ws + off);   off += (size_t)B * sizeof(double);
    off = (off + 255) & ~(size_t)255;
    unsigned* maskBuf    = (unsigned*)(ws + off);
    const size_t maskBytes = (size_t)B * TPB * sizeof(unsigned);
    const bool useMask = (off + maskBytes) <= ws_size;

    k_count<<<B, TPB, 0, stream>>>(score, blockCount, useMask ? maskBuf : nullptr, n);
    if (useMask)
        k_main<true><<<B, TPB, 0, stream>>>(predict, nullptr, maskBuf, blockCount,
                                            blockSum, n, B);
    else
        k_main<false><<<B, TPB, 0, stream>>>(predict, score, nullptr, blockCount,
                                             blockSum, n, B);
    k_final<<<1, TPB, 0, stream>>>(blockSum, (float*)d_out, B);
}

// Round 9
// 38.150 us; speedup vs baseline: 1.1549x; 1.1549x over previous
//
#include <hip/hip_runtime.h>

#define TPB 256
#define PER_THREAD 32
#define CHUNK (TPB * PER_THREAD)     // 8192 elements per block
#define WCHUNK (64 * PER_THREAD)     // 2048 elements per wave
#define NQ 8                         // float4 loads per lane per wave

// ---------------------------------------------------------------------------
// Exclusive block-wide scan of one unsigned per thread (tid order).
// ---------------------------------------------------------------------------
__device__ __forceinline__ unsigned block_excl_scan(unsigned tsum, unsigned* wtot) {
    const int lane = threadIdx.x & 63;
    const int wid  = threadIdx.x >> 6;
    unsigned v = tsum;
#pragma unroll
    for (int off = 1; off < 64; off <<= 1) {
        unsigned u = __shfl_up(v, off, 64);
        if (lane >= off) v += u;
    }
    if (lane == 63) wtot[wid] = v;
    __syncthreads();
    unsigned woff = 0;
    for (int w = 0; w < wid; ++w) woff += wtot[w];
    return woff + v - tsum;   // exclusive prefix for this thread
}

// ---------------------------------------------------------------------------
// Pass 1: wave-coalesced score read (depth-2 ping-pong). Mask word g covers
// elements [32g, 32g+32) in global element order.
// ---------------------------------------------------------------------------
__global__ void k_count(const float* __restrict__ score,
                        unsigned* __restrict__ blockCount,
                        unsigned* __restrict__ mask, long n) {
    const int  tid  = threadIdx.x;
    const int  lane = tid & 63, w = tid >> 6;
    const long base  = (long)blockIdx.x * CHUNK;
    const long wbase = base + (long)w * WCHUNK;
    unsigned cnt = 0;

    if (base + CHUNK <= n) {
        const float4* s4 = reinterpret_cast<const float4*>(score);
        const long ibase = wbase / 4 + lane;
        float4 nxt = s4[ibase];                      // prologue load (q=0)
#pragma unroll
        for (int q = 0; q < NQ; ++q) {
            const float4 v = nxt;
            if (q + 1 < NQ) nxt = s4[ibase + 64 * (q + 1)];   // issue next early
            unsigned nib = (unsigned)(v.x > 0.f)        | ((unsigned)(v.y > 0.f) << 1)
                         | ((unsigned)(v.z > 0.f) << 2) | ((unsigned)(v.w > 0.f) << 3);
            cnt += __popc(nib);
            unsigned part = nib << ((lane & 7) * 4);
            part |= __shfl_xor(part, 1);
            part |= __shfl_xor(part, 2);
            part |= __shfl_xor(part, 4);
            if ((lane & 7) == 0 && mask)
                mask[(wbase >> 5) + 8 * q + (lane >> 3)] = part;
        }
    } else {
        for (int q = 0; q < NQ; ++q) {
            unsigned nib = 0;
#pragma unroll
            for (int j = 0; j < 4; ++j) {
                long gi = wbase + 256 * q + 4 * lane + j;
                if (gi < n && score[gi] > 0.f) nib |= (1u << j);
            }
            cnt += __popc(nib);
            unsigned part = nib << ((lane & 7) * 4);
            part |= __shfl_xor(part, 1);
            part |= __shfl_xor(part, 2);
            part |= __shfl_xor(part, 4);
            if ((lane & 7) == 0 && mask)
                mask[(wbase >> 5) + 8 * q + (lane >> 3)] = part;
        }
    }

#pragma unroll
    for (int off = 32; off > 0; off >>= 1) cnt += __shfl_down(cnt, off, 64);
    __shared__ unsigned wsum[TPB / 64];
    if (lane == 0) wsum[w] = cnt;
    __syncthreads();
    if (tid == 0) {
        unsigned tot = 0;
        for (int i = 0; i < TPB / 64; ++i) tot += wsum[i];
        blockCount[blockIdx.x] = tot;
    }
}

// ---------------------------------------------------------------------------
// Pass 2: coalesced predict loads (depth-2 ping-pong), mask-word distribution
// via 2 shfl per q (proven round-7 scheme). VALU-trimmed math:
//   posv = (p*L - invS*(k+1)) * rcp((k+1)*L)   [one rcp instead of two]
//   ranks kept as exact f32 ints (all values <= 2^24)
//   f32 per-thread accumulation (fixed order, deterministic), f64 block sum.
// No fences, no atomics (rounds 3/5/6 lessons).
// ---------------------------------------------------------------------------
template <bool USE_MASK>
__global__ void k_main(const float* __restrict__ predict,
                       const float* __restrict__ score,
                       const unsigned* __restrict__ mask,
                       const unsigned* __restrict__ blockCount,
                       double* __restrict__ blockSum, long n, int B) {
    const int  tid  = threadIdx.x;
    const int  bid  = blockIdx.x;
    const int  lane = tid & 63, w = tid >> 6;
    const long base  = (long)bid * CHUNK;
    const long wbase = base + (long)w * WCHUNK;
    const bool full  = (base + CHUNK <= n);

    __shared__ unsigned wtot[TPB / 64];
    __shared__ unsigned wpart[2 * (TPB / 64)];
    __shared__ unsigned s_off, s_P;
    __shared__ double   dsum[TPB / 64];

    // --- this thread's mask word (its 32 contiguous elements) ---
    unsigned wd = 0;
    if (USE_MASK) {
        wd = mask[(size_t)bid * TPB + tid];
    } else {
        const long tb = base + (long)tid * PER_THREAD;
        if (tb + PER_THREAD <= n) {
            const float4* s4 = reinterpret_cast<const float4*>(score + tb);
#pragma unroll
            for (int q = 0; q < PER_THREAD / 4; ++q) {
                float4 v = s4[q];
                wd |= ((unsigned)(v.x > 0.f)) << (4 * q + 0);
                wd |= ((unsigned)(v.y > 0.f)) << (4 * q + 1);
                wd |= ((unsigned)(v.z > 0.f)) << (4 * q + 2);
                wd |= ((unsigned)(v.w > 0.f)) << (4 * q + 3);
            }
        } else {
            for (int e = 0; e < PER_THREAD; ++e) {
                long gi = tb + e;
                if (gi < n && score[gi] > 0.f) wd |= (1u << e);
            }
        }
    }

    unsigned cnt  = __popc(wd);
    unsigned excl = block_excl_scan(cnt, wtot);

    // --- per-block exclusive offset + global total P from blockCount ---
    unsigned offp = 0, tot = 0;
    for (int j = tid; j < B; j += TPB) {
        unsigned c = blockCount[j];
        tot  += c;
        offp += (j < bid) ? c : 0u;
    }
#pragma unroll
    for (int off = 32; off > 0; off >>= 1) {
        offp += __shfl_down(offp, off, 64);
        tot  += __shfl_down(tot,  off, 64);
    }
    if (lane == 0) { wpart[2 * w] = offp; wpart[2 * w + 1] = tot; }
    __syncthreads();
    if (tid == 0) {
        unsigned o = 0, t = 0;
        for (int i = 0; i < TPB / 64; ++i) { o += wpart[2 * i]; t += wpart[2 * i + 1]; }
        s_off = o; s_P = t;
    }
    __syncthreads();

    const unsigned P = s_P;
    const float invS = 1.0f / (float)P;                 // s value at positives
    const float sumS = (float)((double)invS * (double)P);
    const float rcpSumS = 1.0f / sumS;
    const float Pf   = (float)P;
    const float Pfp1 = Pf + 1.0f;

    const unsigned pre = s_off + excl;   // positives before this thread's word

    float facc = 0.0f;                   // 32 terms, fixed order: deterministic
    if (full) {
        const float4* p4 = reinterpret_cast<const float4*>(predict);
        const long ibase = wbase / 4 + lane;
        float4 nxt = p4[ibase];                      // prologue load (q=0)
#pragma unroll
        for (int q = 0; q < NQ; ++q) {
            const float4 cur = nxt;
            if (q + 1 < NQ) nxt = p4[ibase + 64 * (q + 1)];   // issue next early
            const int t = 8 * q + (lane >> 3);
            const unsigned wq  = __shfl(wd,  t, 64);
            const unsigned prq = __shfl(pre, t, 64);
            const int nibStart = (lane & 7) * 4;
            const unsigned nib = (wq >> nibStart) & 0xFu;
            // exact f32 integer bookkeeping (all values <= 2^24)
            float kincl = (float)(prq + __popc(wq & ((1u << nibStart) - 1u)));
            const float gp1 = (float)(unsigned)(wbase + 256 * q + 4 * lane + 1);
            const float pv[4] = {cur.x, cur.y, cur.z, cur.w};
#pragma unroll
            for (int j = 0; j < 4; ++j) {
                const bool ispos = (nib >> j) & 1u;
                kincl += ispos ? 1.0f : 0.0f;        // inclusive positive rank
                const float p   = pv[j] * rcpSumS;
                const float kp1 = kincl + 1.0f;
                const float L   = __log2f(kp1);
                const float posv = (p * L - invS * kp1)
                                 * __builtin_amdgcn_rcpf(kp1 * L);
                const float mf   = (gp1 + (float)j) - kincl;  // inclusive neg rank
                const float negv = p * __builtin_amdgcn_rcpf(Pfp1 + mf);
                const float tt = ispos ? posv : negv;
                facc += tt * tt;
            }
        }
    } else {
        unsigned run = pre;
        for (int e = 0; e < PER_THREAD; ++e) {
            const long gi = base + (long)tid * PER_THREAD + e;
            if (gi >= n) break;
            const bool ispos = (wd >> e) & 1u;
            const unsigned newrun = run + (ispos ? 1u : 0u);
            const float p   = predict[gi] * rcpSumS;
            const float kp1 = (float)(newrun + 1u);
            const float L   = __log2f(kp1);
            const float posv = (p * L - invS * kp1)
                             * __builtin_amdgcn_rcpf(kp1 * L);
            const float mf   = (float)(unsigned)(gi + 1 - (long)newrun);
            const float negv = p * __builtin_amdgcn_rcpf(Pf + mf + 1.0f);
            const float tt = ispos ? posv : negv;
            facc += tt * tt;
            run = newrun;
        }
    }

    // --- deterministic block reduce (f64 across threads) ---
    double acc = (double)facc;
#pragma unroll
    for (int off = 32; off > 0; off >>= 1) acc += __shfl_down(acc, off, 64);
    if (lane == 0) dsum[w] = acc;
    __syncthreads();
    if (tid == 0) {
        double t = 0.0;
        for (int i = 0; i < TPB / 64; ++i) t += dsum[i];
        blockSum[bid] = t;
    }
}

// ---------------------------------------------------------------------------
// Pass 3: deterministic reduce of per-block doubles -> float scalar.
// ---------------------------------------------------------------------------
__global__ void k_final(const double* __restrict__ blockSum,
                        float* __restrict__ out, int B) {
    const int tid = threadIdx.x;
    double acc = 0.0;
    for (int j = tid; j < B; j += TPB) acc += blockSum[j];
#pragma unroll
    for (int off = 32; off > 0; off >>= 1) acc += __shfl_down(acc, off, 64);
    __shared__ double dsum[TPB / 64];
    const int lane = tid & 63, wid = tid >> 6;
    if (lane == 0) dsum[wid] = acc;
    __syncthreads();
    if (tid == 0) {
        double tot = 0.0;
        for (int w = 0; w < TPB / 64; ++w) tot += dsum[w];
        out[0] = (float)tot;
    }
}

extern "C" void kernel_launch(void* const* d_in, const int* in_sizes, int n_in,
                              void* d_out, int out_size, void* d_ws, size_t ws_size,
                              hipStream_t stream) {
    const float* predict = (const float*)d_in[0];
    const float* score   = (const float*)d_in[1];
    const long n = (long)in_sizes[0];
    const int B = (int)((n + CHUNK - 1) / CHUNK);   // 2048 for N=2^24

    unsigned char* ws = (unsigned char*)d_ws;
    size_t off = 0;
    unsigned* blockCount = (unsigned*)(ws + off); off += (size_t)B * sizeof(unsigned);
    off = (off + 255) & ~(size_t)255;
    double*   blockSum   = (double*)(ws + off);   off += (size_t)B * sizeof(double);
    off = (off + 255) & ~(size_t)255;
    unsigned* maskBuf    = (unsigned*)(ws + off);
    const size_t maskBytes = (size_t)B * TPB * sizeof(unsigned);
    const bool useMask = (off + maskBytes) <= ws_size;

    k_count<<<B, TPB, 0, stream>>>(score, blockCount, useMask ? maskBuf : nullptr, n);
    if (useMask)
        k_main<true><<<B, TPB, 0, stream>>>(predict, nullptr, maskBuf, blockCount,
                                            blockSum, n, B);
    else
        k_main<false><<<B, TPB, 0, stream>>>(predict, score, nullptr, blockCount,
                                             blockSum, n, B);
    k_final<<<1, TPB, 0, stream>>>(blockSum, (float*)d_out, B);
}

// Round 10
// 35.305 us; speedup vs baseline: 1.2479x; 1.0806x over previous
//
#include <hip/hip_runtime.h>

#define TPB 512
#define PER_THREAD 32
#define CHUNK (TPB * PER_THREAD)     // 16384 elements per block
#define WCHUNK (64 * PER_THREAD)     // 2048 elements per wave
#define NQ 8                         // float4 loads per lane per wave

// ---------------------------------------------------------------------------
// Exclusive block-wide scan of one unsigned per thread (tid order).
// ---------------------------------------------------------------------------
__device__ __forceinline__ unsigned block_excl_scan(unsigned tsum, unsigned* wtot) {
    const int lane = threadIdx.x & 63;
    const int wid  = threadIdx.x >> 6;
    unsigned v = tsum;
#pragma unroll
    for (int off = 1; off < 64; off <<= 1) {
        unsigned u = __shfl_up(v, off, 64);
        if (lane >= off) v += u;
    }
    if (lane == 63) wtot[wid] = v;
    __syncthreads();
    unsigned woff = 0;
    for (int w = 0; w < wid; ++w) woff += wtot[w];
    return woff + v - tsum;   // exclusive prefix for this thread
}

// ---------------------------------------------------------------------------
// Pass 1: wave-coalesced score read (compiler-scheduled, round-7 proven).
// Mask word g covers elements [32g, 32g+32) in global element order.
// ---------------------------------------------------------------------------
__global__ void k_count(const float* __restrict__ score,
                        unsigned* __restrict__ blockCount,
                        unsigned* __restrict__ mask, long n) {
    const int  tid  = threadIdx.x;
    const int  lane = tid & 63, w = tid >> 6;
    const long base  = (long)blockIdx.x * CHUNK;
    const long wbase = base + (long)w * WCHUNK;
    unsigned cnt = 0;

    if (base + CHUNK <= n) {
        const float4* s4 = reinterpret_cast<const float4*>(score);
#pragma unroll
        for (int q = 0; q < NQ; ++q) {
            float4 v = s4[wbase / 4 + 64 * q + lane];
            unsigned nib = (unsigned)(v.x > 0.f)        | ((unsigned)(v.y > 0.f) << 1)
                         | ((unsigned)(v.z > 0.f) << 2) | ((unsigned)(v.w > 0.f) << 3);
            cnt += __popc(nib);
            unsigned part = nib << ((lane & 7) * 4);
            part |= __shfl_xor(part, 1);
            part |= __shfl_xor(part, 2);
            part |= __shfl_xor(part, 4);
            if ((lane & 7) == 0 && mask)
                mask[(wbase >> 5) + 8 * q + (lane >> 3)] = part;
        }
    } else {
        for (int q = 0; q < NQ; ++q) {
            unsigned nib = 0;
#pragma unroll
            for (int j = 0; j < 4; ++j) {
                long gi = wbase + 256 * q + 4 * lane + j;
                if (gi < n && score[gi] > 0.f) nib |= (1u << j);
            }
            cnt += __popc(nib);
            unsigned part = nib << ((lane & 7) * 4);
            part |= __shfl_xor(part, 1);
            part |= __shfl_xor(part, 2);
            part |= __shfl_xor(part, 4);
            if ((lane & 7) == 0 && mask)
                mask[(wbase >> 5) + 8 * q + (lane >> 3)] = part;
        }
    }

#pragma unroll
    for (int off = 32; off > 0; off >>= 1) cnt += __shfl_down(cnt, off, 64);
    __shared__ unsigned wsum[TPB / 64];
    if (lane == 0) wsum[w] = cnt;
    __syncthreads();
    if (tid == 0) {
        unsigned tot = 0;
        for (int i = 0; i < TPB / 64; ++i) tot += wsum[i];
        blockCount[blockIdx.x] = tot;
    }
}

// ---------------------------------------------------------------------------
// Pass 2: round-7 proven scheme at TPB=512. Thread tid's mask word covers
// its 32 contiguous elements; block scan in tid order; wave-coalesced float4
// predict loads with word+prefix fetched via 2 shfl per q.
// No fences, no atomics (rounds 3/5/6 lessons). No forced pipelining
// (rounds 8/9 lessons: compiler schedule + occupancy beat hand MLP).
// ---------------------------------------------------------------------------
template <bool USE_MASK>
__global__ void k_main(const float* __restrict__ predict,
                       const float* __restrict__ score,
                       const unsigned* __restrict__ mask,
                       const unsigned* __restrict__ blockCount,
                       double* __restrict__ blockSum, long n, int B) {
    const int  tid  = threadIdx.x;
    const int  bid  = blockIdx.x;
    const int  lane = tid & 63, w = tid >> 6;
    const long base  = (long)bid * CHUNK;
    const long wbase = base + (long)w * WCHUNK;
    const bool full  = (base + CHUNK <= n);

    __shared__ unsigned wtot[TPB / 64];
    __shared__ unsigned wpart[2 * (TPB / 64)];
    __shared__ unsigned s_off, s_P;
    __shared__ double   dsum[TPB / 64];

    // --- this thread's mask word (its 32 contiguous elements) ---
    unsigned wd = 0;
    if (USE_MASK) {
        wd = mask[(size_t)bid * TPB + tid];
    } else {
        const long tb = base + (long)tid * PER_THREAD;
        if (tb + PER_THREAD <= n) {
            const float4* s4 = reinterpret_cast<const float4*>(score + tb);
#pragma unroll
            for (int q = 0; q < PER_THREAD / 4; ++q) {
                float4 v = s4[q];
                wd |= ((unsigned)(v.x > 0.f)) << (4 * q + 0);
                wd |= ((unsigned)(v.y > 0.f)) << (4 * q + 1);
                wd |= ((unsigned)(v.z > 0.f)) << (4 * q + 2);
                wd |= ((unsigned)(v.w > 0.f)) << (4 * q + 3);
            }
        } else {
            for (int e = 0; e < PER_THREAD; ++e) {
                long gi = tb + e;
                if (gi < n && score[gi] > 0.f) wd |= (1u << e);
            }
        }
    }

    unsigned cnt  = __popc(wd);
    unsigned excl = block_excl_scan(cnt, wtot);

    // --- per-block exclusive offset + global total P from blockCount ---
    unsigned offp = 0, tot = 0;
    for (int j = tid; j < B; j += TPB) {
        unsigned c = blockCount[j];
        tot  += c;
        offp += (j < bid) ? c : 0u;
    }
#pragma unroll
    for (int off = 32; off > 0; off >>= 1) {
        offp += __shfl_down(offp, off, 64);
        tot  += __shfl_down(tot,  off, 64);
    }
    if (lane == 0) { wpart[2 * w] = offp; wpart[2 * w + 1] = tot; }
    __syncthreads();
    if (tid == 0) {
        unsigned o = 0, t = 0;
        for (int i = 0; i < TPB / 64; ++i) { o += wpart[2 * i]; t += wpart[2 * i + 1]; }
        s_off = o; s_P = t;
    }
    __syncthreads();

    const unsigned P = s_P;
    const float invS = 1.0f / (float)P;                 // s value at positives
    const float sumS = (float)((double)invS * (double)P);
    const float rcpSumS = 1.0f / sumS;
    const float Pf = (float)P;

    const unsigned pre = s_off + excl;   // positives before this thread's word

    double acc = 0.0;
    if (full) {
        const float4* p4 = reinterpret_cast<const float4*>(predict);
#pragma unroll
        for (int q = 0; q < NQ; ++q) {
            const int t = 8 * q + (lane >> 3);
            const unsigned wq  = __shfl(wd,  t, 64);
            const unsigned prq = __shfl(pre, t, 64);
            const int nibStart = (lane & 7) * 4;
            unsigned run = prq + __popc(wq & ((1u << nibStart) - 1u));
            const unsigned nib = (wq >> nibStart) & 0xFu;
            float4 pv4 = p4[wbase / 4 + 64 * q + lane];
            float pv[4] = {pv4.x, pv4.y, pv4.z, pv4.w};
#pragma unroll
            for (int j = 0; j < 4; ++j) {
                const bool ispos = (nib >> j) & 1u;
                const unsigned newrun = run + (ispos ? 1u : 0u);
                const long gi = wbase + 256 * q + 4 * lane + j;
                const float p = pv[j] * rcpSumS;
                const float kp1  = (float)(newrun + 1u);
                const float posv = p * __builtin_amdgcn_rcpf(kp1)
                                 - invS * __builtin_amdgcn_rcpf(__log2f(kp1));
                const unsigned mr = (unsigned)(gi + 1) - newrun;
                const float negv  = p * __builtin_amdgcn_rcpf(Pf + (float)mr + 1.0f);
                const float tt = ispos ? posv : negv;
                acc += (double)(tt * tt);
                run = newrun;
            }
        }
    } else {
        for (int q = 0; q < NQ; ++q) {
            const int t = 8 * q + (lane >> 3);
            const unsigned wq  = __shfl(wd,  t, 64);
            const unsigned prq = __shfl(pre, t, 64);
            const int nibStart = (lane & 7) * 4;
            unsigned run = prq + __popc(wq & ((1u << nibStart) - 1u));
            const unsigned nib = (wq >> nibStart) & 0xFu;
            for (int j = 0; j < 4; ++j) {
                const long gi = wbase + 256 * q + 4 * lane + j;
                if (gi >= n) continue;
                const bool ispos = (nib >> j) & 1u;
                const unsigned newrun = run + (ispos ? 1u : 0u);
                const float p = predict[gi] * rcpSumS;
                const float kp1  = (float)(newrun + 1u);
                const float posv = p * __builtin_amdgcn_rcpf(kp1)
                                 - invS * __builtin_amdgcn_rcpf(__log2f(kp1));
                const unsigned mr = (unsigned)(gi + 1) - newrun;
                const float negv  = p * __builtin_amdgcn_rcpf(Pf + (float)mr + 1.0f);
                const float tt = ispos ? posv : negv;
                acc += (double)(tt * tt);
                run = newrun;
            }
        }
    }

    // --- deterministic block reduce ---
#pragma unroll
    for (int off = 32; off > 0; off >>= 1) acc += __shfl_down(acc, off, 64);
    if (lane == 0) dsum[w] = acc;
    __syncthreads();
    if (tid == 0) {
        double t = 0.0;
        for (int i = 0; i < TPB / 64; ++i) t += dsum[i];
        blockSum[bid] = t;
    }
}

// ---------------------------------------------------------------------------
// Pass 3: deterministic reduce of per-block doubles -> float scalar.
// ---------------------------------------------------------------------------
__global__ void k_final(const double* __restrict__ blockSum,
                        float* __restrict__ out, int B) {
    const int tid = threadIdx.x;
    double acc = 0.0;
    for (int j = tid; j < B; j += TPB) acc += blockSum[j];
#pragma unroll
    for (int off = 32; off > 0; off >>= 1) acc += __shfl_down(acc, off, 64);
    __shared__ double dsum[TPB / 64];
    const int lane = tid & 63, wid = tid >> 6;
    if (lane == 0) dsum[wid] = acc;
    __syncthreads();
    if (tid == 0) {
        double tot = 0.0;
        for (int w = 0; w < TPB / 64; ++w) tot += dsum[w];
        out[0] = (float)tot;
    }
}

extern "C" void kernel_launch(void* const* d_in, const int* in_sizes, int n_in,
                              void* d_out, int out_size, void* d_ws, size_t ws_size,
                              hipStream_t stream) {
    const float* predict = (const float*)d_in[0];
    const float* score   = (const float*)d_in[1];
    const long n = (long)in_sizes[0];
    const int B = (int)((n + CHUNK - 1) / CHUNK);   // 1024 for N=2^24

    unsigned char* ws = (unsigned char*)d_ws;
    size_t off = 0;
    unsigned* blockCount = (unsigned*)(ws + off); off += (size_t)B * sizeof(unsigned);
    off = (off + 255) & ~(size_t)255;
    double*   blockSum   = (double*)(ws + off);   off += (size_t)B * sizeof(double);
    off = (off + 255) & ~(size_t)255;
    unsigned* maskBuf    = (unsigned*)(ws + off);
    const size_t maskBytes = (size_t)B * TPB * sizeof(unsigned);
    const bool useMask = (off + maskBytes) <= ws_size;

    k_count<<<B, TPB, 0, stream>>>(score, blockCount, useMask ? maskBuf : nullptr, n);
    if (useMask)
        k_main<true><<<B, TPB, 0, stream>>>(predict, nullptr, maskBuf, blockCount,
                                            blockSum, n, B);
    else
        k_main<false><<<B, TPB, 0, stream>>>(predict, score, nullptr, blockCount,
                                             blockSum, n, B);
    k_final<<<1, TPB, 0, stream>>>(blockSum, (float*)d_out, B);
}